// Round 4
// baseline (451.335 us; speedup 1.0000x reference)
//
#include <hip/hip_runtime.h>

#define NN 80000
#define NE 1280000
#define F  64
#define NBLK ((NN + 1023) / 1024)   // 79 scan blocks

// ---------------------------------------------------------------------------
// edge_index dtype sniffer: int64 (reference) vs int32 (harness doc).
// ---------------------------------------------------------------------------
__global__ void detect_idx64(const int* __restrict__ idx, int* __restrict__ flag) {
    __shared__ int allzero;
    if (threadIdx.x == 0) allzero = 1;
    __syncthreads();
    if (idx[2 * threadIdx.x + 1] != 0) allzero = 0;
    __syncthreads();
    if (threadIdx.x == 0) *flag = allzero;
}

__device__ __forceinline__ int ld_src(const int* __restrict__ idx, int e, int is64) {
    return is64 ? idx[2 * e] : idx[e];
}
__device__ __forceinline__ int ld_dst(const int* __restrict__ idx, int e, int is64) {
    return is64 ? idx[2 * NE + 2 * e] : idx[NE + e];
}

__global__ void deg_kernel(const int* __restrict__ idx, const int* __restrict__ flag,
                           int* __restrict__ deg) {
    int e = blockIdx.x * blockDim.x + threadIdx.x;
    if (e >= NE) return;
    int is64 = *flag;
    atomicAdd(&deg[ld_dst(idx, e, is64)], 1);
}

__global__ void dinv_kernel(const int* __restrict__ deg, float* __restrict__ dinv) {
    int n = blockIdx.x * blockDim.x + threadIdx.x;
    if (n >= NN) return;
    dinv[n] = rsqrtf((float)(deg[n] + 1));   // +1 = self loop
}

// y0 = X * dinv[row]  (prescale for layer-1 gather)
__global__ void prescale_kernel(const float* __restrict__ x, const float* __restrict__ dinv,
                                float* __restrict__ y) {
    int tid = blockIdx.x * blockDim.x + threadIdx.x;   // NN*16 threads
    if (tid >= NN * 16) return;
    int n = tid >> 4, q = tid & 15;
    float c = dinv[n];
    float4 v = ((const float4*)(x + (size_t)n * F))[q];
    v.x *= c; v.y *= c; v.z *= c; v.w *= c;
    ((float4*)(y + (size_t)n * F))[q] = v;
}

// ---- 3-phase parallel exclusive scan of deg -> row_ptr ----
__global__ __launch_bounds__(1024) void scan_partial(const int* __restrict__ deg,
                                                     int* __restrict__ row_ptr,
                                                     int* __restrict__ bsum) {
    __shared__ int wsum[16];
    int i = blockIdx.x * 1024 + threadIdx.x;
    int lane = threadIdx.x & 63, wv = threadIdx.x >> 6;
    int v = (i < NN) ? deg[i] : 0;
    int incl = v;
    #pragma unroll
    for (int d = 1; d < 64; d <<= 1) {
        int t = __shfl_up(incl, d, 64);
        if (lane >= d) incl += t;
    }
    if (lane == 63) wsum[wv] = incl;
    __syncthreads();
    int woff = 0;
    for (int w = 0; w < wv; ++w) woff += wsum[w];
    if (i < NN) row_ptr[i] = woff + incl - v;       // local exclusive
    if (threadIdx.x == 1023) bsum[blockIdx.x] = woff + incl;
}

__global__ void scan_bsum(int* __restrict__ bsum) {   // 1 wave
    int lane = threadIdx.x;
    int carry = 0;
    for (int base = 0; base < NBLK; base += 64) {
        int v = (base + lane < NBLK) ? bsum[base + lane] : 0;
        int incl = v;
        #pragma unroll
        for (int d = 1; d < 64; d <<= 1) {
            int t = __shfl_up(incl, d, 64);
            if (lane >= d) incl += t;
        }
        if (base + lane < NBLK) bsum[base + lane] = carry + incl - v;
        carry += __shfl(incl, 63);
    }
}

__global__ void scan_apply(const int* __restrict__ bsum, int* __restrict__ row_ptr,
                           int* __restrict__ cursor) {
    int i = blockIdx.x * 256 + threadIdx.x;
    if (i >= NN) {
        if (i == NN) row_ptr[NN] = NE;
        return;
    }
    int v = row_ptr[i] + bsum[i >> 10];
    row_ptr[i] = v;
    cursor[i] = v;
}

// Counting-sort edges by dst: edata[pos] = src  (4 B/edge)
__global__ void sort_kernel(const int* __restrict__ idx, const int* __restrict__ flag,
                            int* __restrict__ cursor, int* __restrict__ edata) {
    int e = blockIdx.x * blockDim.x + threadIdx.x;
    if (e >= NE) return;
    int is64 = *flag;
    int s = ld_src(idx, e, is64);
    int d = ld_dst(idx, e, is64);
    int pos = atomicAdd(&cursor[d], 1);
    edata[pos] = s;
}

// CSR gather, pure sum: out[n] = dinv[n] * (y[n] + sum y[src]).
// One wave per node; 16 lanes x float4 per edge slot; 4 slots/wave; 4x unroll.
__global__ __launch_bounds__(256) void gather_kernel(const float* __restrict__ y,
        const int* __restrict__ edata, const int* __restrict__ row_ptr,
        const float* __restrict__ dinv, float* __restrict__ out) {
    int n = blockIdx.x * 4 + (threadIdx.x >> 6);   // grid = NN/4 exact
    int lane = threadIdx.x & 63;
    int sub = lane >> 4;        // edge slot 0..3
    int fl  = lane & 15;        // float4 index within feature row
    int p0 = row_ptr[n], p1 = row_ptr[n + 1];
    float4 acc = make_float4(0.f, 0.f, 0.f, 0.f);
    for (int base = p0; base < p1; base += 16) {
        int   s[4];
        float m[4];
        #pragma unroll
        for (int j = 0; j < 4; ++j) {
            int q = base + j * 4 + sub;
            int qc = q < p1 ? q : p1 - 1;          // p1 > base >= p0 here
            s[j] = edata[qc];
            m[j] = (q < p1) ? 1.f : 0.f;
        }
        float4 v[4];
        #pragma unroll
        for (int j = 0; j < 4; ++j)
            v[j] = ((const float4*)(y + (size_t)s[j] * F))[fl];
        #pragma unroll
        for (int j = 0; j < 4; ++j) {
            acc.x = fmaf(m[j], v[j].x, acc.x);
            acc.y = fmaf(m[j], v[j].y, acc.y);
            acc.z = fmaf(m[j], v[j].z, acc.z);
            acc.w = fmaf(m[j], v[j].w, acc.w);
        }
    }
    // reduce the 4 slots: lanes l, l+16, l+32, l+48 -> lane l
    acc.x += __shfl_down(acc.x, 32); acc.y += __shfl_down(acc.y, 32);
    acc.z += __shfl_down(acc.z, 32); acc.w += __shfl_down(acc.w, 32);
    acc.x += __shfl_down(acc.x, 16); acc.y += __shfl_down(acc.y, 16);
    acc.z += __shfl_down(acc.z, 16); acc.w += __shfl_down(acc.w, 16);
    if (sub == 0) {
        float dv = dinv[n];
        float4 self = ((const float4*)(y + (size_t)n * F))[fl];
        float4 r;
        r.x = dv * (acc.x + self.x);
        r.y = dv * (acc.y + self.y);
        r.z = dv * (acc.z + self.z);
        r.w = dv * (acc.w + self.w);
        ((float4*)(out + (size_t)n * F))[fl] = r;
    }
}

// C = relu?(A @ W + b), optionally row-scaled by dinv (producing y for next gather).
template <int RELU, int SCALE>
__global__ __launch_bounds__(256) void gemm64(const float* __restrict__ A,
        const float* __restrict__ W, const float* __restrict__ b,
        const float* __restrict__ dinv, float* __restrict__ C) {
    __shared__ float Ws[64 * 64];
    __shared__ float xs[32 * 64];
    int col = threadIdx.x & 63;
    int rg  = threadIdx.x >> 6;          // rows rg*8 .. rg*8+7
    for (int i = threadIdx.x; i < 64 * 64 / 4; i += 256)
        ((float4*)Ws)[i] = ((const float4*)W)[i];
    int row0 = blockIdx.x * 32;
    for (int i = threadIdx.x; i < 32 * 64 / 4; i += 256)
        ((float4*)xs)[i] = ((const float4*)(A + (size_t)row0 * F))[i];
    __syncthreads();
    float acc[8];
    #pragma unroll
    for (int r = 0; r < 8; ++r) acc[r] = 0.f;
    for (int k = 0; k < 64; ++k) {
        float wk = Ws[k * 64 + col];
        #pragma unroll
        for (int r = 0; r < 8; ++r)
            acc[r] = fmaf(xs[(rg * 8 + r) * 64 + k], wk, acc[r]);
    }
    float bias = b[col];
    #pragma unroll
    for (int r = 0; r < 8; ++r) {
        float v = acc[r] + bias;
        if (RELU) v = fmaxf(v, 0.f);
        if (SCALE) v *= dinv[row0 + rg * 8 + r];
        C[(size_t)(row0 + rg * 8 + r) * F + col] = v;
    }
}

extern "C" void kernel_launch(void* const* d_in, const int* in_sizes, int n_in,
                              void* d_out, int out_size, void* d_ws, size_t ws_size,
                              hipStream_t stream) {
    const float* X  = (const float*)d_in[0];
    const int*  idx = (const int*)d_in[1];
    const float* W1 = (const float*)d_in[2];
    const float* b1 = (const float*)d_in[3];
    const float* W2 = (const float*)d_in[4];
    const float* b2 = (const float*)d_in[5];
    const float* W3 = (const float*)d_in[6];
    const float* b3 = (const float*)d_in[7];
    float* out = (float*)d_out;

    char* ws = (char*)d_ws;
    int*   flag    = (int*)(ws + 0);
    int*   bsum    = (int*)(ws + 256);
    int*   deg     = (int*)(ws + 1024);
    float* dinv    = (float*)(ws + 321024);
    int*   row_ptr = (int*)(ws + 641024);                // NN+1 ints
    int*   cursor  = (int*)(ws + 961280);
    int*   edata   = (int*)(ws + 1281280);               // NE * 4 B
    float* bufY    = (float*)(ws + 6401280);             // [NN,64] gather input
    float* bufA    = (float*)(ws + 26881280);            // [NN,64] gather output
    // total ws use ~47.4 MB

    hipMemsetAsync(deg, 0, NN * sizeof(int), stream);
    detect_idx64<<<1, 1024, 0, stream>>>(idx, flag);
    deg_kernel<<<(NE + 255) / 256, 256, 0, stream>>>(idx, flag, deg);
    dinv_kernel<<<(NN + 255) / 256, 256, 0, stream>>>(deg, dinv);
    scan_partial<<<NBLK, 1024, 0, stream>>>(deg, row_ptr, bsum);
    scan_bsum<<<1, 64, 0, stream>>>(bsum);
    scan_apply<<<(NN + 256) / 256, 256, 0, stream>>>(bsum, row_ptr, cursor);
    sort_kernel<<<(NE + 255) / 256, 256, 0, stream>>>(idx, flag, cursor, edata);
    prescale_kernel<<<(NN * 16) / 256, 256, 0, stream>>>(X, dinv, bufY);

    const int gatherBlocks = NN / 4;     // 20000
    const int gemmBlocks   = NN / 32;    // 2500

    // layer 1: agg -> bufA ; y1 = dinv*relu(bufA@W1+b1) -> bufY
    gather_kernel<<<gatherBlocks, 256, 0, stream>>>(bufY, edata, row_ptr, dinv, bufA);
    gemm64<1, 1><<<gemmBlocks, 256, 0, stream>>>(bufA, W1, b1, dinv, bufY);
    // layer 2
    gather_kernel<<<gatherBlocks, 256, 0, stream>>>(bufY, edata, row_ptr, dinv, bufA);
    gemm64<1, 1><<<gemmBlocks, 256, 0, stream>>>(bufA, W2, b2, dinv, bufY);
    // layer 3: plain output (no relu, no scale)
    gather_kernel<<<gatherBlocks, 256, 0, stream>>>(bufY, edata, row_ptr, dinv, bufA);
    gemm64<0, 0><<<gemmBlocks, 256, 0, stream>>>(bufA, W3, b3, dinv, out);
}

// Round 5
// 330.599 us; speedup vs baseline: 1.3652x; 1.3652x over previous
//
#include <hip/hip_runtime.h>

#define NN 80000
#define NE 1280000
#define F  64
#define BSH 9                        // 512 nodes per bucket
#define NB  157                      // ceil(NN / 512)
#define CAP 12288                    // per-bucket ebuf capacity (avg 8153, +45 sigma)
#define EPB 5120                     // edges per partition block
#define EPT 20                       // edges per thread (EPB / 256)
#define PBLK (NE / EPB)              // 250 partition blocks, exact

// ---------------------------------------------------------------------------
// edge_index dtype sniffer: int64 (reference) vs int32 (harness doc).
// ---------------------------------------------------------------------------
__global__ void detect_idx64(const int* __restrict__ idx, int* __restrict__ flag) {
    __shared__ int allzero;
    if (threadIdx.x == 0) allzero = 1;
    __syncthreads();
    if (idx[2 * threadIdx.x + 1] != 0) allzero = 0;
    __syncthreads();
    if (threadIdx.x == 0) *flag = allzero;
}

__device__ __forceinline__ int ld_src(const int* __restrict__ idx, int e, int is64) {
    return is64 ? idx[2 * e] : idx[e];
}
__device__ __forceinline__ int ld_dst(const int* __restrict__ idx, int e, int is64) {
    return is64 ? idx[2 * NE + 2 * e] : idx[NE + e];
}

// ---------------------------------------------------------------------------
// Pass 1: partition edges into NB dst-buckets. LDS-staged so global writes
// land in ~32-edge contiguous runs. ebuf[b*CAP + j] = (dstoff<<17) | src.
// bcur[b] accumulates bucket counts (global cursors, memset to 0 first).
// ---------------------------------------------------------------------------
__global__ __launch_bounds__(256) void partition_kernel(
        const int* __restrict__ idx, const int* __restrict__ flag,
        int* __restrict__ bcur, int* __restrict__ ebuf) {
    __shared__ int cnt[NB];
    __shared__ int lbase[NB];
    __shared__ int gbase[NB];
    __shared__ int lds_val[EPB];
    __shared__ int lds_gaddr[EPB];
    int tid = threadIdx.x;
    for (int i = tid; i < NB; i += 256) cnt[i] = 0;
    __syncthreads();
    int is64 = *flag;
    int e0 = blockIdx.x * EPB;
    int val[EPT], br[EPT];
    #pragma unroll
    for (int j = 0; j < EPT; ++j) {
        int e = e0 + j * 256 + tid;
        int s = ld_src(idx, e, is64);
        int d = ld_dst(idx, e, is64);
        int b = d >> BSH;
        val[j] = ((d & ((1 << BSH) - 1)) << 17) | s;
        int r = atomicAdd(&cnt[b], 1);       // rank within (block, bucket)
        br[j] = (b << 13) | r;               // r < 5120 < 2^13
    }
    __syncthreads();
    // wave 0: exclusive scan cnt -> lbase; threads 64..: reserve global runs
    if (tid < 64) {
        int carry = 0;
        for (int base = 0; base < NB; base += 64) {
            int i2 = base + tid;
            int v = (i2 < NB) ? cnt[i2] : 0;
            int incl = v;
            #pragma unroll
            for (int d2 = 1; d2 < 64; d2 <<= 1) {
                int t = __shfl_up(incl, d2, 64);
                if (tid >= d2) incl += t;
            }
            if (i2 < NB) lbase[i2] = carry + incl - v;
            carry += __shfl(incl, 63);
        }
    } else if (tid - 64 < NB) {
        int b = tid - 64;
        gbase[b] = atomicAdd(&bcur[b], cnt[b]);
    }
    __syncthreads();
    #pragma unroll
    for (int j = 0; j < EPT; ++j) {
        int b = br[j] >> 13, r = br[j] & 8191;
        int slot = lbase[b] + r;
        int g = gbase[b] + r;
        lds_val[slot]   = val[j];
        lds_gaddr[slot] = (g < CAP) ? (b * CAP + g) : -1;   // overflow guard
    }
    __syncthreads();
    for (int i = tid; i < EPB; i += 256) {
        int a = lds_gaddr[i];
        if (a >= 0) ebuf[a] = lds_val[i];    // runs of ~32 consecutive addrs
    }
}

// ---------------------------------------------------------------------------
// Pass 2: one block per bucket. LDS counting sort by dst-within-bucket;
// emits final CSR edata (coalesced), row_ptr, and dinv (deg from histogram).
// ---------------------------------------------------------------------------
__global__ __launch_bounds__(256) void bucket_sort_kernel(
        const int* __restrict__ bcur, const int* __restrict__ ebuf,
        int* __restrict__ edata, int* __restrict__ row_ptr,
        float* __restrict__ dinv) {
    __shared__ int cnt[512];
    __shared__ int off[512];
    __shared__ int lds_out[CAP];
    __shared__ int ebase_s;
    int b = blockIdx.x, tid = threadIdx.x;
    cnt[tid] = 0; cnt[tid + 256] = 0;
    // ebase = sum of min(bcur[j],CAP) for j<b  (wave 0)
    if (tid < 64) {
        int carry = 0;
        for (int base = 0; base < NB; base += 64) {
            int i2 = base + tid;
            int v = (i2 < NB) ? min(bcur[i2], CAP) : 0;
            int incl = v;
            #pragma unroll
            for (int d2 = 1; d2 < 64; d2 <<= 1) {
                int t = __shfl_up(incl, d2, 64);
                if (tid >= d2) incl += t;
            }
            if (i2 == b) ebase_s = carry + incl - v;
            carry += __shfl(incl, 63);
        }
    }
    __syncthreads();
    int bcnt = min(bcur[b], CAP);
    int ebase = ebase_s;
    const int* src = ebuf + b * CAP;
    // histogram over dst-within-bucket
    for (int i = tid; i < bcnt; i += 256)
        atomicAdd(&cnt[src[i] >> 17], 1);
    __syncthreads();
    // wave 0: exclusive scan of 512 counters
    if (tid < 64) {
        int carry = 0;
        #pragma unroll
        for (int base = 0; base < 512; base += 64) {
            int v = cnt[base + tid];
            int incl = v;
            #pragma unroll
            for (int d2 = 1; d2 < 64; d2 <<= 1) {
                int t = __shfl_up(incl, d2, 64);
                if (tid >= d2) incl += t;
            }
            off[base + tid] = carry + incl - v;
            carry += __shfl(incl, 63);
        }
    }
    __syncthreads();
    // row_ptr + dinv for this bucket's nodes
    int n0 = b << BSH;
    for (int i = tid; i < 512; i += 256) {
        int n = n0 + i;
        if (n < NN) {
            row_ptr[n] = ebase + off[i];
            dinv[n] = rsqrtf((float)cnt[i] + 1.f);
        } else if (n == NN) {
            row_ptr[NN] = ebase + off[i];
        }
    }
    __syncthreads();
    // LDS scatter (off doubles as cursor), then coalesced flush
    for (int i = tid; i < bcnt; i += 256) {
        int w = src[i];                       // L2-hot re-read
        int pos = atomicAdd(&off[w >> 17], 1);
        lds_out[pos] = w & 0x1FFFF;
    }
    __syncthreads();
    for (int i = tid; i < bcnt; i += 256)
        edata[ebase + i] = lds_out[i];
}

// y0 = X * dinv[row]  (prescale for layer-1 gather)
__global__ void prescale_kernel(const float* __restrict__ x, const float* __restrict__ dinv,
                                float* __restrict__ y) {
    int tid = blockIdx.x * blockDim.x + threadIdx.x;   // NN*16 threads
    if (tid >= NN * 16) return;
    int n = tid >> 4, q = tid & 15;
    float c = dinv[n];
    float4 v = ((const float4*)(x + (size_t)n * F))[q];
    v.x *= c; v.y *= c; v.z *= c; v.w *= c;
    ((float4*)(y + (size_t)n * F))[q] = v;
}

// CSR gather, pure sum: out[n] = dinv[n] * (y[n] + sum y[src]).
// One wave per node; 16 lanes x float4 per edge slot; 4 slots/wave; 4x unroll.
__global__ __launch_bounds__(256) void gather_kernel(const float* __restrict__ y,
        const int* __restrict__ edata, const int* __restrict__ row_ptr,
        const float* __restrict__ dinv, float* __restrict__ out) {
    int n = blockIdx.x * 4 + (threadIdx.x >> 6);   // grid = NN/4 exact
    int lane = threadIdx.x & 63;
    int sub = lane >> 4;        // edge slot 0..3
    int fl  = lane & 15;        // float4 index within feature row
    int p0 = row_ptr[n], p1 = row_ptr[n + 1];
    float4 acc = make_float4(0.f, 0.f, 0.f, 0.f);
    for (int base = p0; base < p1; base += 16) {
        int   s[4];
        float m[4];
        #pragma unroll
        for (int j = 0; j < 4; ++j) {
            int q = base + j * 4 + sub;
            int qc = q < p1 ? q : p1 - 1;          // p1 > base >= p0 here
            s[j] = edata[qc];
            m[j] = (q < p1) ? 1.f : 0.f;
        }
        float4 v[4];
        #pragma unroll
        for (int j = 0; j < 4; ++j)
            v[j] = ((const float4*)(y + (size_t)s[j] * F))[fl];
        #pragma unroll
        for (int j = 0; j < 4; ++j) {
            acc.x = fmaf(m[j], v[j].x, acc.x);
            acc.y = fmaf(m[j], v[j].y, acc.y);
            acc.z = fmaf(m[j], v[j].z, acc.z);
            acc.w = fmaf(m[j], v[j].w, acc.w);
        }
    }
    acc.x += __shfl_down(acc.x, 32); acc.y += __shfl_down(acc.y, 32);
    acc.z += __shfl_down(acc.z, 32); acc.w += __shfl_down(acc.w, 32);
    acc.x += __shfl_down(acc.x, 16); acc.y += __shfl_down(acc.y, 16);
    acc.z += __shfl_down(acc.z, 16); acc.w += __shfl_down(acc.w, 16);
    if (sub == 0) {
        float dv = dinv[n];
        float4 self = ((const float4*)(y + (size_t)n * F))[fl];
        float4 r;
        r.x = dv * (acc.x + self.x);
        r.y = dv * (acc.y + self.y);
        r.z = dv * (acc.z + self.z);
        r.w = dv * (acc.w + self.w);
        ((float4*)(out + (size_t)n * F))[fl] = r;
    }
}

// C = relu?(A @ W + b), optionally row-scaled by dinv (producing y for next gather).
template <int RELU, int SCALE>
__global__ __launch_bounds__(256) void gemm64(const float* __restrict__ A,
        const float* __restrict__ W, const float* __restrict__ b,
        const float* __restrict__ dinv, float* __restrict__ C) {
    __shared__ float Ws[64 * 64];
    __shared__ float xs[32 * 64];
    int col = threadIdx.x & 63;
    int rg  = threadIdx.x >> 6;          // rows rg*8 .. rg*8+7
    for (int i = threadIdx.x; i < 64 * 64 / 4; i += 256)
        ((float4*)Ws)[i] = ((const float4*)W)[i];
    int row0 = blockIdx.x * 32;
    for (int i = threadIdx.x; i < 32 * 64 / 4; i += 256)
        ((float4*)xs)[i] = ((const float4*)(A + (size_t)row0 * F))[i];
    __syncthreads();
    float acc[8];
    #pragma unroll
    for (int r = 0; r < 8; ++r) acc[r] = 0.f;
    for (int k = 0; k < 64; ++k) {
        float wk = Ws[k * 64 + col];
        #pragma unroll
        for (int r = 0; r < 8; ++r)
            acc[r] = fmaf(xs[(rg * 8 + r) * 64 + k], wk, acc[r]);
    }
    float bias = b[col];
    #pragma unroll
    for (int r = 0; r < 8; ++r) {
        float v = acc[r] + bias;
        if (RELU) v = fmaxf(v, 0.f);
        if (SCALE) v *= dinv[row0 + rg * 8 + r];
        C[(size_t)(row0 + rg * 8 + r) * F + col] = v;
    }
}

extern "C" void kernel_launch(void* const* d_in, const int* in_sizes, int n_in,
                              void* d_out, int out_size, void* d_ws, size_t ws_size,
                              hipStream_t stream) {
    const float* X  = (const float*)d_in[0];
    const int*  idx = (const int*)d_in[1];
    const float* W1 = (const float*)d_in[2];
    const float* b1 = (const float*)d_in[3];
    const float* W2 = (const float*)d_in[4];
    const float* b2 = (const float*)d_in[5];
    const float* W3 = (const float*)d_in[6];
    const float* b3 = (const float*)d_in[7];
    float* out = (float*)d_out;

    char* ws = (char*)d_ws;
    int*   flag    = (int*)(ws + 0);
    int*   bcur    = (int*)(ws + 256);                    // NB ints
    int*   row_ptr = (int*)(ws + 1024);                   // NN+1 ints
    int*   dinv_i  = (int*)(ws + 321280);
    float* dinv    = (float*)dinv_i;                      // NN floats
    int*   edata   = (int*)(ws + 641536);                 // NE ints (final CSR)
    float* bufY    = (float*)(ws + 5761536);              // [NN,64]
    float* bufA    = (float*)(ws + 26241536);             // [NN,64]
    int*   ebuf    = (int*)bufA;                          // aliases bufA (7.7 MB,
                                                          // dead before gather L1 writes)
    // total ws use ~46.7 MB

    hipMemsetAsync(bcur, 0, NB * sizeof(int), stream);
    detect_idx64<<<1, 1024, 0, stream>>>(idx, flag);
    partition_kernel<<<PBLK, 256, 0, stream>>>(idx, flag, bcur, ebuf);
    bucket_sort_kernel<<<NB, 256, 0, stream>>>(bcur, ebuf, edata, row_ptr, dinv);
    prescale_kernel<<<(NN * 16) / 256, 256, 0, stream>>>(X, dinv, bufY);

    const int gatherBlocks = NN / 4;     // 20000
    const int gemmBlocks   = NN / 32;    // 2500

    // layer 1: agg -> bufA ; y1 = dinv*relu(bufA@W1+b1) -> bufY
    gather_kernel<<<gatherBlocks, 256, 0, stream>>>(bufY, edata, row_ptr, dinv, bufA);
    gemm64<1, 1><<<gemmBlocks, 256, 0, stream>>>(bufA, W1, b1, dinv, bufY);
    // layer 2
    gather_kernel<<<gatherBlocks, 256, 0, stream>>>(bufY, edata, row_ptr, dinv, bufA);
    gemm64<1, 1><<<gemmBlocks, 256, 0, stream>>>(bufA, W2, b2, dinv, bufY);
    // layer 3: plain output (no relu, no scale)
    gather_kernel<<<gatherBlocks, 256, 0, stream>>>(bufY, edata, row_ptr, dinv, bufA);
    gemm64<0, 0><<<gemmBlocks, 256, 0, stream>>>(bufA, W3, b3, dinv, out);
}

// Round 6
// 291.567 us; speedup vs baseline: 1.5480x; 1.1339x over previous
//
#include <hip/hip_runtime.h>

#define NN 80000
#define NE 1280000
#define F  64
#define BSH 9                        // 512 nodes per bucket
#define NB  157                      // ceil(NN / 512)
#define CAP 12288                    // per-bucket ebuf capacity (avg 8153)
#define EPB 5120                     // edges per partition block
#define EPT 20                       // EPB / 256
#define PBLK (NE / EPB)              // 250

typedef unsigned short ushort_t;
typedef unsigned int uint_t;

__device__ __forceinline__ float bflo(uint_t u) { return __uint_as_float(u << 16); }
__device__ __forceinline__ float bfhi(uint_t u) { return __uint_as_float(u & 0xFFFF0000u); }
__device__ __forceinline__ uint_t f2bf(float f) {            // RNE bf16 (finite inputs)
    uint_t u = __float_as_uint(f);
    return (u + 0x7FFFu + ((u >> 16) & 1u)) >> 16;
}

// ---------------------------------------------------------------------------
// edge_index dtype sniffer: int64 (reference) vs int32 (harness doc).
// ---------------------------------------------------------------------------
__global__ void detect_idx64(const int* __restrict__ idx, int* __restrict__ flag) {
    __shared__ int allzero;
    if (threadIdx.x == 0) allzero = 1;
    __syncthreads();
    if (idx[2 * threadIdx.x + 1] != 0) allzero = 0;
    __syncthreads();
    if (threadIdx.x == 0) *flag = allzero;
}

__device__ __forceinline__ int ld_src(const int* __restrict__ idx, int e, int is64) {
    return is64 ? idx[2 * e] : idx[e];
}
__device__ __forceinline__ int ld_dst(const int* __restrict__ idx, int e, int is64) {
    return is64 ? idx[2 * NE + 2 * e] : idx[NE + e];
}

// ---------------------------------------------------------------------------
// Pass 1: partition edges into NB dst-buckets via LDS staging (cache-granular
// global writes). ebuf[b*CAP + j] = (dstoff<<17) | src.
// ---------------------------------------------------------------------------
__global__ __launch_bounds__(256) void partition_kernel(
        const int* __restrict__ idx, const int* __restrict__ flag,
        int* __restrict__ bcur, int* __restrict__ ebuf) {
    __shared__ int cnt[NB];
    __shared__ int lbase[NB];
    __shared__ int gbase[NB];
    __shared__ int lds_val[EPB];
    __shared__ int lds_gaddr[EPB];
    int tid = threadIdx.x;
    for (int i = tid; i < NB; i += 256) cnt[i] = 0;
    __syncthreads();
    int is64 = *flag;
    int e0 = blockIdx.x * EPB;
    int val[EPT], br[EPT];
    #pragma unroll
    for (int j = 0; j < EPT; ++j) {
        int e = e0 + j * 256 + tid;
        int s = ld_src(idx, e, is64);
        int d = ld_dst(idx, e, is64);
        int b = d >> BSH;
        val[j] = ((d & ((1 << BSH) - 1)) << 17) | s;
        int r = atomicAdd(&cnt[b], 1);
        br[j] = (b << 13) | r;
    }
    __syncthreads();
    if (tid < 64) {
        int carry = 0;
        for (int base = 0; base < NB; base += 64) {
            int i2 = base + tid;
            int v = (i2 < NB) ? cnt[i2] : 0;
            int incl = v;
            #pragma unroll
            for (int d2 = 1; d2 < 64; d2 <<= 1) {
                int t = __shfl_up(incl, d2, 64);
                if (tid >= d2) incl += t;
            }
            if (i2 < NB) lbase[i2] = carry + incl - v;
            carry += __shfl(incl, 63);
        }
    } else if (tid - 64 < NB) {
        int b = tid - 64;
        gbase[b] = atomicAdd(&bcur[b], cnt[b]);
    }
    __syncthreads();
    #pragma unroll
    for (int j = 0; j < EPT; ++j) {
        int b = br[j] >> 13, r = br[j] & 8191;
        int slot = lbase[b] + r;
        int g = gbase[b] + r;
        lds_val[slot]   = val[j];
        lds_gaddr[slot] = (g < CAP) ? (b * CAP + g) : -1;
    }
    __syncthreads();
    for (int i = tid; i < EPB; i += 256) {
        int a = lds_gaddr[i];
        if (a >= 0) ebuf[a] = lds_val[i];
    }
}

// ---------------------------------------------------------------------------
// Pass 2: per-bucket LDS counting sort -> final CSR edata + row_ptr + dinv.
// ---------------------------------------------------------------------------
__global__ __launch_bounds__(256) void bucket_sort_kernel(
        const int* __restrict__ bcur, const int* __restrict__ ebuf,
        int* __restrict__ edata, int* __restrict__ row_ptr,
        float* __restrict__ dinv) {
    __shared__ int cnt[512];
    __shared__ int off[512];
    __shared__ int lds_out[CAP];
    __shared__ int ebase_s;
    int b = blockIdx.x, tid = threadIdx.x;
    cnt[tid] = 0; cnt[tid + 256] = 0;
    if (tid < 64) {
        int carry = 0;
        for (int base = 0; base < NB; base += 64) {
            int i2 = base + tid;
            int v = (i2 < NB) ? min(bcur[i2], CAP) : 0;
            int incl = v;
            #pragma unroll
            for (int d2 = 1; d2 < 64; d2 <<= 1) {
                int t = __shfl_up(incl, d2, 64);
                if (tid >= d2) incl += t;
            }
            if (i2 == b) ebase_s = carry + incl - v;
            carry += __shfl(incl, 63);
        }
    }
    __syncthreads();
    int bcnt = min(bcur[b], CAP);
    int ebase = ebase_s;
    const int* src = ebuf + b * CAP;
    for (int i = tid; i < bcnt; i += 256)
        atomicAdd(&cnt[src[i] >> 17], 1);
    __syncthreads();
    if (tid < 64) {
        int carry = 0;
        #pragma unroll
        for (int base = 0; base < 512; base += 64) {
            int v = cnt[base + tid];
            int incl = v;
            #pragma unroll
            for (int d2 = 1; d2 < 64; d2 <<= 1) {
                int t = __shfl_up(incl, d2, 64);
                if (tid >= d2) incl += t;
            }
            off[base + tid] = carry + incl - v;
            carry += __shfl(incl, 63);
        }
    }
    __syncthreads();
    int n0 = b << BSH;
    for (int i = tid; i < 512; i += 256) {
        int n = n0 + i;
        if (n < NN) {
            row_ptr[n] = ebase + off[i];
            dinv[n] = rsqrtf((float)cnt[i] + 1.f);
        } else if (n == NN) {
            row_ptr[NN] = ebase + off[i];
        }
    }
    __syncthreads();
    for (int i = tid; i < bcnt; i += 256) {
        int w = src[i];
        int pos = atomicAdd(&off[w >> 17], 1);
        lds_out[pos] = w & 0x1FFFF;
    }
    __syncthreads();
    for (int i = tid; i < bcnt; i += 256)
        edata[ebase + i] = lds_out[i];
}

// y0 = bf16(X * dinv[row])
__global__ void prescale_kernel(const float* __restrict__ x, const float* __restrict__ dinv,
                                ushort_t* __restrict__ y) {
    int tid = blockIdx.x * blockDim.x + threadIdx.x;   // NN*16 threads
    if (tid >= NN * 16) return;
    int n = tid >> 4, q = tid & 15;
    float c = dinv[n];
    float4 v = ((const float4*)(x + (size_t)n * F))[q];
    uint2 o;
    o.x = f2bf(v.x * c) | (f2bf(v.y * c) << 16);
    o.y = f2bf(v.z * c) | (f2bf(v.w * c) << 16);
    ((uint2*)(y + (size_t)n * F))[q] = o;
}

// ---------------------------------------------------------------------------
// Fused layer: CSR gather (bf16 y, fp32 acc) -> LDS tile -> 64x64 GEMM with
// bias(+ReLU)(+dinv scale) epilogue -> bf16 y_next (or fp32 final output).
// Block = 256 threads = 4 nodes; wave per node; 4 edge-slots x 16 lanes.
// ---------------------------------------------------------------------------
template <int RELU, int SCALE, int LAST>
__global__ __launch_bounds__(256) void gcn_layer(
        const ushort_t* __restrict__ y, const int* __restrict__ edata,
        const int* __restrict__ row_ptr, const float* __restrict__ dinv,
        const float* __restrict__ W, const float* __restrict__ bias,
        ushort_t* __restrict__ out_bf, float* __restrict__ out_f32) {
    __shared__ float Ws[64 * 64];   // 16 KB
    __shared__ float xs[4][64];     // 1 KB
    int tid = threadIdx.x;
    for (int i = tid; i < 1024; i += 256)            // stage W (L1-hot)
        ((float4*)Ws)[i] = ((const float4*)W)[i];
    int wv = tid >> 6, lane = tid & 63;
    int sub = lane >> 4, fl = lane & 15;
    int n = blockIdx.x * 4 + wv;                     // grid = NN/4 exact
    int p0 = row_ptr[n], p1 = row_ptr[n + 1];
    float a0 = 0.f, a1 = 0.f, a2 = 0.f, a3 = 0.f;
    for (int base = p0; base < p1; base += 16) {
        int s[4]; float m[4];
        #pragma unroll
        for (int j = 0; j < 4; ++j) {
            int q = base + j * 4 + sub;
            int qc = q < p1 ? q : p1 - 1;            // p1 > base here
            s[j] = edata[qc];
            m[j] = (q < p1) ? 1.f : 0.f;
        }
        uint2 u[4];
        #pragma unroll
        for (int j = 0; j < 4; ++j)
            u[j] = ((const uint2*)(y + (size_t)s[j] * F))[fl];
        #pragma unroll
        for (int j = 0; j < 4; ++j) {
            a0 = fmaf(m[j], bflo(u[j].x), a0);
            a1 = fmaf(m[j], bfhi(u[j].x), a1);
            a2 = fmaf(m[j], bflo(u[j].y), a2);
            a3 = fmaf(m[j], bfhi(u[j].y), a3);
        }
    }
    a0 += __shfl_down(a0, 32); a1 += __shfl_down(a1, 32);
    a2 += __shfl_down(a2, 32); a3 += __shfl_down(a3, 32);
    a0 += __shfl_down(a0, 16); a1 += __shfl_down(a1, 16);
    a2 += __shfl_down(a2, 16); a3 += __shfl_down(a3, 16);
    if (sub == 0) {
        float dv = dinv[n];
        uint2 us = ((const uint2*)(y + (size_t)n * F))[fl];
        float4 r;
        r.x = dv * (a0 + bflo(us.x));
        r.y = dv * (a1 + bfhi(us.x));
        r.z = dv * (a2 + bflo(us.y));
        r.w = dv * (a3 + bfhi(us.y));
        ((float4*)&xs[wv][0])[fl] = r;
    }
    __syncthreads();
    // GEMM phase: wave wv computes row n, lane = output column.
    float acc = 0.f;
    #pragma unroll
    for (int k = 0; k < 64; ++k)
        acc = fmaf(xs[wv][k], Ws[k * 64 + lane], acc);   // xs broadcast; Ws 2-way (free)
    float v = acc + bias[lane];
    if (RELU) v = fmaxf(v, 0.f);
    if (SCALE) v *= dinv[n];
    if (LAST) out_f32[(size_t)n * F + lane] = v;
    else      out_bf[(size_t)n * F + lane] = (ushort_t)f2bf(v);
}

extern "C" void kernel_launch(void* const* d_in, const int* in_sizes, int n_in,
                              void* d_out, int out_size, void* d_ws, size_t ws_size,
                              hipStream_t stream) {
    const float* X  = (const float*)d_in[0];
    const int*  idx = (const int*)d_in[1];
    const float* W1 = (const float*)d_in[2];
    const float* b1 = (const float*)d_in[3];
    const float* W2 = (const float*)d_in[4];
    const float* b2 = (const float*)d_in[5];
    const float* W3 = (const float*)d_in[6];
    const float* b3 = (const float*)d_in[7];
    float* out = (float*)d_out;

    char* ws = (char*)d_ws;
    int*      flag    = (int*)(ws + 0);
    int*      bcur    = (int*)(ws + 256);                 // NB ints
    int*      row_ptr = (int*)(ws + 1024);                // NN+1 ints
    float*    dinv    = (float*)(ws + 321280);            // NN floats
    int*      edata   = (int*)(ws + 641536);              // NE ints (final CSR)
    ushort_t* ybufA   = (ushort_t*)(ws + 5761536);        // [NN,64] bf16
    ushort_t* ybufB   = (ushort_t*)(ws + 16001536);       // [NN,64] bf16
    int*      ebuf    = (int*)(ws + 26241536);            // NB*CAP ints (7.7 MB)
    // total ws use ~34 MB

    hipMemsetAsync(bcur, 0, NB * sizeof(int), stream);
    detect_idx64<<<1, 1024, 0, stream>>>(idx, flag);
    partition_kernel<<<PBLK, 256, 0, stream>>>(idx, flag, bcur, ebuf);
    bucket_sort_kernel<<<NB, 256, 0, stream>>>(bcur, ebuf, edata, row_ptr, dinv);
    prescale_kernel<<<(NN * 16) / 256, 256, 0, stream>>>(X, dinv, ybufA);

    const int layerBlocks = NN / 4;   // 20000

    // layer 1: y1 = bf16( dinv * relu( agg(y0) @ W1 + b1 ) )
    gcn_layer<1, 1, 0><<<layerBlocks, 256, 0, stream>>>(
        ybufA, edata, row_ptr, dinv, W1, b1, ybufB, nullptr);
    // layer 2
    gcn_layer<1, 1, 0><<<layerBlocks, 256, 0, stream>>>(
        ybufB, edata, row_ptr, dinv, W2, b2, ybufA, nullptr);
    // layer 3: fp32 output, no relu / no scale
    gcn_layer<0, 0, 1><<<layerBlocks, 256, 0, stream>>>(
        ybufA, edata, row_ptr, dinv, W3, b3, nullptr, out);
}

// Round 7
// 246.456 us; speedup vs baseline: 1.8313x; 1.1830x over previous
//
#include <hip/hip_runtime.h>
#include <hip/hip_fp16.h>

#define NN 80000
#define NE 1280000
#define F  64
#define BSH 9                        // 512 nodes per bucket
#define NB  157                      // ceil(NN / 512)
#define CAP 12288                    // per-bucket ebuf capacity (avg 8153)
#define EPB 5120                     // edges per partition block
#define EPT 20                       // EPB / 256
#define PBLK (NE / EPB)              // 250
#define LBLK (NN / 64)               // 1250 layer blocks, exact

typedef _Float16 half_t;
typedef _Float16 half8 __attribute__((ext_vector_type(8)));
typedef float f32x4 __attribute__((ext_vector_type(4)));
typedef unsigned int uint_t;

// ---------------------------------------------------------------------------
// edge_index dtype sniffer: int64 (reference) vs int32 (harness doc).
// ---------------------------------------------------------------------------
__global__ void detect_idx64(const int* __restrict__ idx, int* __restrict__ flag) {
    __shared__ int allzero;
    if (threadIdx.x == 0) allzero = 1;
    __syncthreads();
    if (idx[2 * threadIdx.x + 1] != 0) allzero = 0;
    __syncthreads();
    if (threadIdx.x == 0) *flag = allzero;
}

__device__ __forceinline__ int ld_src(const int* __restrict__ idx, int e, int is64) {
    return is64 ? idx[2 * e] : idx[e];
}
__device__ __forceinline__ int ld_dst(const int* __restrict__ idx, int e, int is64) {
    return is64 ? idx[2 * NE + 2 * e] : idx[NE + e];
}

// ---------------------------------------------------------------------------
// Pass 1: partition edges into NB dst-buckets via LDS staging (cache-granular
// global writes). ebuf[b*CAP + j] = (dstoff<<17) | src.
// ---------------------------------------------------------------------------
__global__ __launch_bounds__(256) void partition_kernel(
        const int* __restrict__ idx, const int* __restrict__ flag,
        int* __restrict__ bcur, int* __restrict__ ebuf) {
    __shared__ int cnt[NB];
    __shared__ int lbase[NB];
    __shared__ int gbase[NB];
    __shared__ int lds_val[EPB];
    __shared__ int lds_gaddr[EPB];
    int tid = threadIdx.x;
    for (int i = tid; i < NB; i += 256) cnt[i] = 0;
    __syncthreads();
    int is64 = *flag;
    int e0 = blockIdx.x * EPB;
    int val[EPT], br[EPT];
    #pragma unroll
    for (int j = 0; j < EPT; ++j) {
        int e = e0 + j * 256 + tid;
        int s = ld_src(idx, e, is64);
        int d = ld_dst(idx, e, is64);
        int b = d >> BSH;
        val[j] = ((d & ((1 << BSH) - 1)) << 17) | s;
        int r = atomicAdd(&cnt[b], 1);
        br[j] = (b << 13) | r;
    }
    __syncthreads();
    if (tid < 64) {
        int carry = 0;
        for (int base = 0; base < NB; base += 64) {
            int i2 = base + tid;
            int v = (i2 < NB) ? cnt[i2] : 0;
            int incl = v;
            #pragma unroll
            for (int d2 = 1; d2 < 64; d2 <<= 1) {
                int t = __shfl_up(incl, d2, 64);
                if (tid >= d2) incl += t;
            }
            if (i2 < NB) lbase[i2] = carry + incl - v;
            carry += __shfl(incl, 63);
        }
    } else if (tid - 64 < NB) {
        int b = tid - 64;
        gbase[b] = atomicAdd(&bcur[b], cnt[b]);
    }
    __syncthreads();
    #pragma unroll
    for (int j = 0; j < EPT; ++j) {
        int b = br[j] >> 13, r = br[j] & 8191;
        int slot = lbase[b] + r;
        int g = gbase[b] + r;
        lds_val[slot]   = val[j];
        lds_gaddr[slot] = (g < CAP) ? (b * CAP + g) : -1;
    }
    __syncthreads();
    for (int i = tid; i < EPB; i += 256) {
        int a = lds_gaddr[i];
        if (a >= 0) ebuf[a] = lds_val[i];
    }
}

// ---------------------------------------------------------------------------
// Pass 2: per-bucket LDS counting sort -> final CSR edata + row_ptr + dinv.
// ---------------------------------------------------------------------------
__global__ __launch_bounds__(256) void bucket_sort_kernel(
        const int* __restrict__ bcur, const int* __restrict__ ebuf,
        int* __restrict__ edata, int* __restrict__ row_ptr,
        float* __restrict__ dinv) {
    __shared__ int cnt[512];
    __shared__ int off[512];
    __shared__ int lds_out[CAP];
    __shared__ int ebase_s;
    int b = blockIdx.x, tid = threadIdx.x;
    cnt[tid] = 0; cnt[tid + 256] = 0;
    if (tid < 64) {
        int carry = 0;
        for (int base = 0; base < NB; base += 64) {
            int i2 = base + tid;
            int v = (i2 < NB) ? min(bcur[i2], CAP) : 0;
            int incl = v;
            #pragma unroll
            for (int d2 = 1; d2 < 64; d2 <<= 1) {
                int t = __shfl_up(incl, d2, 64);
                if (tid >= d2) incl += t;
            }
            if (i2 == b) ebase_s = carry + incl - v;
            carry += __shfl(incl, 63);
        }
    }
    __syncthreads();
    int bcnt = min(bcur[b], CAP);
    int ebase = ebase_s;
    const int* src = ebuf + b * CAP;
    for (int i = tid; i < bcnt; i += 256)
        atomicAdd(&cnt[src[i] >> 17], 1);
    __syncthreads();
    if (tid < 64) {
        int carry = 0;
        #pragma unroll
        for (int base = 0; base < 512; base += 64) {
            int v = cnt[base + tid];
            int incl = v;
            #pragma unroll
            for (int d2 = 1; d2 < 64; d2 <<= 1) {
                int t = __shfl_up(incl, d2, 64);
                if (tid >= d2) incl += t;
            }
            off[base + tid] = carry + incl - v;
            carry += __shfl(incl, 63);
        }
    }
    __syncthreads();
    int n0 = b << BSH;
    for (int i = tid; i < 512; i += 256) {
        int n = n0 + i;
        if (n < NN) {
            row_ptr[n] = ebase + off[i];
            dinv[n] = rsqrtf((float)cnt[i] + 1.f);
        } else if (n == NN) {
            row_ptr[NN] = ebase + off[i];
        }
    }
    __syncthreads();
    for (int i = tid; i < bcnt; i += 256) {
        int w = src[i];
        int pos = atomicAdd(&off[w >> 17], 1);
        lds_out[pos] = w & 0x1FFFF;
    }
    __syncthreads();
    for (int i = tid; i < bcnt; i += 256)
        edata[ebase + i] = lds_out[i];
}

// y0 = fp16(X * dinv[row])
__global__ void prescale_kernel(const float* __restrict__ x, const float* __restrict__ dinv,
                                half_t* __restrict__ y) {
    int tid = blockIdx.x * blockDim.x + threadIdx.x;   // NN*16 threads
    if (tid >= NN * 16) return;
    int n = tid >> 4, q = tid & 15;
    float c = dinv[n];
    float4 v = ((const float4*)(x + (size_t)n * F))[q];
    half_t h[4] = { (half_t)(v.x * c), (half_t)(v.y * c),
                    (half_t)(v.z * c), (half_t)(v.w * c) };
    ((uint2*)(y + (size_t)n * F))[q] = *(uint2*)h;
}

__device__ __forceinline__ float2 h2f2(uint_t u) {
    __half2 h = *(__half2*)&u;
    return __half22float2(h);
}

// ---------------------------------------------------------------------------
// Fused layer, 64 nodes/block: CSR gather (fp16 y, fp32 acc) -> fp16 LDS tile
// -> MFMA 16x16x32_f16 GEMM (W^T staged once per block) -> epilogue
// (bias/ReLU/dinv) -> fp16 y_next or fp32 final output.
// ---------------------------------------------------------------------------
template <int RELU, int SCALE, int LAST>
__global__ __launch_bounds__(256) void gcn_layer(
        const half_t* __restrict__ y, const int* __restrict__ edata,
        const int* __restrict__ row_ptr, const float* __restrict__ dinv,
        const float* __restrict__ W, const float* __restrict__ bias,
        half_t* __restrict__ out_h, float* __restrict__ out_f32) {
    __shared__ half_t Wt[64][72];    // W^T, fp16, padded   (9216 B)
    __shared__ half_t xt[64][72];    // aggregated rows     (9216 B)
    int tid = threadIdx.x;
    // stage W^T (one-time; L2-hot source)
    for (int i = tid; i < 4096; i += 256) {
        int k = i >> 6, n2 = i & 63;
        Wt[n2][k] = (half_t)W[i];
    }
    int wv = tid >> 6, lane = tid & 63;
    int sub = lane >> 4, fl = lane & 15;
    int n0 = blockIdx.x * 64;
    // ---- gather phase: wave wv aggregates nodes n0+wv*16 .. +15 ----
    for (int i = 0; i < 16; ++i) {
        int n = n0 + wv * 16 + i;
        int p0 = row_ptr[n], p1 = row_ptr[n + 1];
        float a0 = 0.f, a1 = 0.f, a2 = 0.f, a3 = 0.f;
        for (int base = p0; base < p1; base += 16) {
            int s[4]; float m[4];
            #pragma unroll
            for (int j = 0; j < 4; ++j) {
                int q = base + j * 4 + sub;
                int qc = q < p1 ? q : p1 - 1;
                s[j] = edata[qc];
                m[j] = (q < p1) ? 1.f : 0.f;
            }
            uint2 u[4];
            #pragma unroll
            for (int j = 0; j < 4; ++j)
                u[j] = ((const uint2*)(y + (size_t)s[j] * F))[fl];
            #pragma unroll
            for (int j = 0; j < 4; ++j) {
                float2 lo = h2f2(u[j].x), hi = h2f2(u[j].y);
                a0 = fmaf(m[j], lo.x, a0);
                a1 = fmaf(m[j], lo.y, a1);
                a2 = fmaf(m[j], hi.x, a2);
                a3 = fmaf(m[j], hi.y, a3);
            }
        }
        a0 += __shfl_down(a0, 32); a1 += __shfl_down(a1, 32);
        a2 += __shfl_down(a2, 32); a3 += __shfl_down(a3, 32);
        a0 += __shfl_down(a0, 16); a1 += __shfl_down(a1, 16);
        a2 += __shfl_down(a2, 16); a3 += __shfl_down(a3, 16);
        if (sub == 0) {
            float dv = dinv[n];
            uint2 us = ((const uint2*)(y + (size_t)n * F))[fl];
            float2 slo = h2f2(us.x), shi = h2f2(us.y);
            half_t h[4] = { (half_t)(dv * (a0 + slo.x)), (half_t)(dv * (a1 + slo.y)),
                            (half_t)(dv * (a2 + shi.x)), (half_t)(dv * (a3 + shi.y)) };
            ((uint2*)&xt[wv * 16 + i][0])[fl] = *(uint2*)h;
        }
    }
    __syncthreads();
    // ---- MFMA phase: wave wv computes rows wv*16..wv*16+15, all 64 cols ----
    int m = lane & 15, q = lane >> 4;
    const half_t* arow = &xt[wv * 16 + m][q * 8];
    half8 A0 = *(const half8*)arow;
    half8 A1 = *(const half8*)(arow + 32);
    #pragma unroll
    for (int ct = 0; ct < 4; ++ct) {
        const half_t* brow = &Wt[ct * 16 + m][q * 8];
        half8 B0 = *(const half8*)brow;
        half8 B1 = *(const half8*)(brow + 32);
        f32x4 c = {0.f, 0.f, 0.f, 0.f};
        c = __builtin_amdgcn_mfma_f32_16x16x32_f16(A0, B0, c, 0, 0, 0);
        c = __builtin_amdgcn_mfma_f32_16x16x32_f16(A1, B1, c, 0, 0, 0);
        float bv = bias[ct * 16 + m];      // col = ct*16 + (lane&15)
        #pragma unroll
        for (int r = 0; r < 4; ++r) {
            int row = n0 + wv * 16 + q * 4 + r;   // C/D: row = quad*4 + reg
            float v = c[r] + bv;
            if (RELU) v = fmaxf(v, 0.f);
            if (SCALE) v *= dinv[row];
            int col = ct * 16 + m;
            if (LAST) out_f32[(size_t)row * F + col] = v;
            else      out_h[(size_t)row * F + col] = (half_t)v;
        }
    }
}

extern "C" void kernel_launch(void* const* d_in, const int* in_sizes, int n_in,
                              void* d_out, int out_size, void* d_ws, size_t ws_size,
                              hipStream_t stream) {
    const float* X  = (const float*)d_in[0];
    const int*  idx = (const int*)d_in[1];
    const float* W1 = (const float*)d_in[2];
    const float* b1 = (const float*)d_in[3];
    const float* W2 = (const float*)d_in[4];
    const float* b2 = (const float*)d_in[5];
    const float* W3 = (const float*)d_in[6];
    const float* b3 = (const float*)d_in[7];
    float* out = (float*)d_out;

    char* ws = (char*)d_ws;
    int*    flag    = (int*)(ws + 0);
    int*    bcur    = (int*)(ws + 256);                 // NB ints
    int*    row_ptr = (int*)(ws + 1024);                // NN+1 ints
    float*  dinv    = (float*)(ws + 321280);            // NN floats
    int*    edata   = (int*)(ws + 641536);              // NE ints (final CSR)
    half_t* ybufA   = (half_t*)(ws + 5761536);          // [NN,64] fp16
    half_t* ybufB   = (half_t*)(ws + 16001536);         // [NN,64] fp16
    int*    ebuf    = (int*)(ws + 26241536);            // NB*CAP ints (7.7 MB)
    // total ws use ~34 MB

    hipMemsetAsync(bcur, 0, NB * sizeof(int), stream);
    detect_idx64<<<1, 1024, 0, stream>>>(idx, flag);
    partition_kernel<<<PBLK, 256, 0, stream>>>(idx, flag, bcur, ebuf);
    bucket_sort_kernel<<<NB, 256, 0, stream>>>(bcur, ebuf, edata, row_ptr, dinv);
    prescale_kernel<<<(NN * 16) / 256, 256, 0, stream>>>(X, dinv, ybufA);

    // layer 1: y1 = fp16( dinv * relu( agg(y0) @ W1 + b1 ) )
    gcn_layer<1, 1, 0><<<LBLK, 256, 0, stream>>>(
        ybufA, edata, row_ptr, dinv, W1, b1, ybufB, nullptr);
    // layer 2
    gcn_layer<1, 1, 0><<<LBLK, 256, 0, stream>>>(
        ybufB, edata, row_ptr, dinv, W2, b2, ybufA, nullptr);
    // layer 3: fp32 output, no relu / no scale
    gcn_layer<0, 0, 1><<<LBLK, 256, 0, stream>>>(
        ybufA, edata, row_ptr, dinv, W3, b3, nullptr, out);
}